// Round 2
// 1093.595 us; speedup vs baseline: 1.9989x; 1.9989x over previous
//
#include <hip/hip_runtime.h>
#include <stdint.h>

#define LOG2F 0.693147180559945f

typedef __attribute__((ext_vector_type(8))) short short8;
typedef __attribute__((ext_vector_type(4))) float f32x4;

// shifted softplus: softplus(x) - log(2), stable form
__device__ __forceinline__ float ssp(float x){
  float t = __expf(-fabsf(x));
  return fmaxf(x, 0.0f) + __logf(1.0f + t) - LOG2F;
}

// fp32 -> bf16 round-to-nearest-even (16-bit pattern in low bits)
__device__ __forceinline__ uint32_t bf16rn(float x){
  uint32_t u = __float_as_uint(x);
  return (u + 0x7fffu + ((u >> 16) & 1u)) >> 16;
}
// split x ~= hi + lo (both bf16). hi RNE, lo = RNE(x - hi): ~16 mantissa bits kept.
__device__ __forceinline__ void split2(float x, unsigned short &h, unsigned short &l){
  uint32_t hb = bf16rn(x);
  h = (unsigned short)hb;
  float hf = __uint_as_float(hb << 16);
  l = (unsigned short)bf16rn(x - hf);
}

// ============================================================================
// MFMA fragment packing (mfma_f32_16x16x32_bf16):
//   A-frag: lane l, elem i <- A[l&15][(l>>4)*8 + i]
//   B-frag: lane l, elem i <- B[(l>>4)*8 + i][l&15]
//   (identical positional k-map for A and B => any HW k-permutation cancels)
//   C/D   : lane l, reg  r -> C[(l>>4)*4 + r][l&15]   (HW-measured, guide §3)
// Split-bf16 GEMM: D += Ah*Bh + Ah*Bl + Al*Bh  (3 MFMAs, fp32 accumulate)
// ============================================================================

// ---------- W pre-conversion into split-bf16 B-fragment layout ----------
// wjf: [ct=8][s=4][hl=2][lane=64] x short8   (64 KB)
// wgf: [ct=8][hl=2][lane=64]      x short8   (16 KB)
__global__ __launch_bounds__(256) void k_wconv(
    const float* __restrict__ Wj, const float* __restrict__ Wg,
    unsigned short* __restrict__ wjf, unsigned short* __restrict__ wgf)
{
  int t = blockIdx.x * 256 + threadIdx.x;
  if (t < 2048){                       // Wj frags: 8 ct * 4 s * 64 lanes
    int lane = t & 63, s = (t >> 6) & 3, ct = t >> 8;
    int col = ct * 16 + (lane & 15);
    int k0  = s * 32 + (lane >> 4) * 8;
    union { unsigned short u[8]; uint4 v; } H, L;
#pragma unroll
    for (int i = 0; i < 8; ++i) split2(Wj[(size_t)(k0 + i) * 128 + col], H.u[i], L.u[i]);
    ((uint4*)wjf)[((ct * 4 + s) * 2 + 0) * 64 + lane] = H.v;
    ((uint4*)wjf)[((ct * 4 + s) * 2 + 1) * 64 + lane] = L.v;
  } else if (t < 2560){                // Wg frags: 8 ct * 64 lanes
    int u = t - 2048, lane = u & 63, ct = u >> 6;
    int col = ct * 16 + (lane & 15);
    int k0  = (lane >> 4) * 8;
    union { unsigned short u8[8]; uint4 v; } H, L;
#pragma unroll
    for (int i = 0; i < 8; ++i) split2(Wg[(size_t)(k0 + i) * 128 + col], H.u8[i], L.u8[i]);
    ((uint4*)wgf)[(ct * 2 + 0) * 64 + lane] = H.v;
    ((uint4*)wgf)[(ct * 2 + 1) * 64 + lane] = L.v;
  }
}

// ---------- edge kernel: vacc[idx_i] += ssp(ssp(x)[idx_j]@Wj + bj) * (g@Wg) ----------
// 32 edges/block, 256 threads = 4 waves. Wave w owns col-tiles {2w, 2w+1}.
// A-frags staged in LDS (XOR-swizzled slots), B-frags streamed from global (L2-hot).
__global__ __launch_bounds__(256) void k_edge(
    const float* __restrict__ x, const float* __restrict__ g,
    const int* __restrict__ idx_i, const int* __restrict__ idx_j,
    const short8* __restrict__ wjf, const short8* __restrict__ wgf,
    const float* __restrict__ bj, float* vacc, int E)
{
  // slot(hl,q,row) = hl*512 + q*32 + (row ^ q)   (q<=15 so XOR stays in [0,32))
  __shared__ short8 ahl[1024];   // 16 KB: message A, 32 rows x 128 k, hi+lo
  __shared__ short8 ghl[256];    //  4 KB: gate A,    32 rows x  32 k, hi+lo
  __shared__ int    ii_s[32];

  const int t    = threadIdx.x;
  const int lane = t & 63;
  const int w    = t >> 6;
  const int l15  = lane & 15;
  const int lq   = lane >> 4;
  const int e0   = blockIdx.x * 32;

  // --- stage A = split(ssp(x[idx_j])) : thread t -> row t>>3, k-segment (t&7)*16 ---
  {
    const int row = t >> 3, kseg = t & 7;
    int e = e0 + row; if (e >= E) e = E - 1;
    const int j = idx_j[e];
    const float4* xp = (const float4*)(x + (size_t)j * 128 + kseg * 16);
    short8 fh0, fh1, fl0, fl1;
#pragma unroll
    for (int q = 0; q < 4; ++q){
      float4 f4 = xp[q];
      float vv[4] = {f4.x, f4.y, f4.z, f4.w};
#pragma unroll
      for (int uu = 0; uu < 4; ++uu){
        unsigned short hh, ll;
        split2(ssp(vv[uu]), hh, ll);
        int i = q * 4 + uu;
        if (i < 8){ fh0[i]   = (short)hh; fl0[i]   = (short)ll; }
        else      { fh1[i-8] = (short)hh; fl1[i-8] = (short)ll; }
      }
    }
    const int q0 = kseg * 2;
    ahl[0*512 + (q0+0)*32 + (row ^ (q0+0))] = fh0;
    ahl[0*512 + (q0+1)*32 + (row ^ (q0+1))] = fh1;
    ahl[1*512 + (q0+0)*32 + (row ^ (q0+0))] = fl0;
    ahl[1*512 + (q0+1)*32 + (row ^ (q0+1))] = fl1;
  }
  // --- stage gate rows g[e][0..31] (no activation) ---
  if (t < 64){
    const int row = t >> 1, kseg = t & 1;
    int e = e0 + row; if (e >= E) e = E - 1;
    const float4* gp = (const float4*)(g + (size_t)e * 32 + kseg * 16);
    short8 fh0, fh1, fl0, fl1;
#pragma unroll
    for (int q = 0; q < 4; ++q){
      float4 f4 = gp[q];
      float vv[4] = {f4.x, f4.y, f4.z, f4.w};
#pragma unroll
      for (int uu = 0; uu < 4; ++uu){
        unsigned short hh, ll;
        split2(vv[uu], hh, ll);
        int i = q * 4 + uu;
        if (i < 8){ fh0[i]   = (short)hh; fl0[i]   = (short)ll; }
        else      { fh1[i-8] = (short)hh; fl1[i-8] = (short)ll; }
      }
    }
    const int q0 = kseg * 2;
    ghl[0*128 + (q0+0)*32 + (row ^ (q0+0))] = fh0;
    ghl[0*128 + (q0+1)*32 + (row ^ (q0+1))] = fh1;
    ghl[1*128 + (q0+0)*32 + (row ^ (q0+0))] = fl0;
    ghl[1*128 + (q0+1)*32 + (row ^ (q0+1))] = fl1;
  }
  if (t >= 64 && t < 96){
    int rr = t - 64; int e = e0 + rr;
    ii_s[rr] = (e < E) ? idx_i[e] : -1;
  }
  __syncthreads();

  // --- MFMA: message (K=128) and gate (K=32), split-bf16 3x ---
  f32x4 am[2][2], ag[2][2];
#pragma unroll
  for (int a = 0; a < 2; ++a)
#pragma unroll
    for (int b = 0; b < 2; ++b){
      am[a][b] = (f32x4){0.f, 0.f, 0.f, 0.f};
      ag[a][b] = (f32x4){0.f, 0.f, 0.f, 0.f};
    }

#pragma unroll
  for (int s = 0; s < 4; ++s){
    const int q = s * 4 + lq;
    short8 a0h = ahl[0*512 + q*32 + ((l15     ) ^ q)];
    short8 a0l = ahl[1*512 + q*32 + ((l15     ) ^ q)];
    short8 a1h = ahl[0*512 + q*32 + ((16 + l15) ^ q)];
    short8 a1l = ahl[1*512 + q*32 + ((16 + l15) ^ q)];
#pragma unroll
    for (int c = 0; c < 2; ++c){
      const int ct = w * 2 + c;
      short8 bh = wjf[((ct*4 + s)*2 + 0)*64 + lane];
      short8 bl = wjf[((ct*4 + s)*2 + 1)*64 + lane];
      am[0][c] = __builtin_amdgcn_mfma_f32_16x16x32_bf16(a0h, bh, am[0][c], 0, 0, 0);
      am[0][c] = __builtin_amdgcn_mfma_f32_16x16x32_bf16(a0h, bl, am[0][c], 0, 0, 0);
      am[0][c] = __builtin_amdgcn_mfma_f32_16x16x32_bf16(a0l, bh, am[0][c], 0, 0, 0);
      am[1][c] = __builtin_amdgcn_mfma_f32_16x16x32_bf16(a1h, bh, am[1][c], 0, 0, 0);
      am[1][c] = __builtin_amdgcn_mfma_f32_16x16x32_bf16(a1h, bl, am[1][c], 0, 0, 0);
      am[1][c] = __builtin_amdgcn_mfma_f32_16x16x32_bf16(a1l, bh, am[1][c], 0, 0, 0);
    }
  }
  {
    const int q = lq;
    short8 g0h = ghl[0*128 + q*32 + ((l15     ) ^ q)];
    short8 g0l = ghl[1*128 + q*32 + ((l15     ) ^ q)];
    short8 g1h = ghl[0*128 + q*32 + ((16 + l15) ^ q)];
    short8 g1l = ghl[1*128 + q*32 + ((16 + l15) ^ q)];
#pragma unroll
    for (int c = 0; c < 2; ++c){
      const int ct = w * 2 + c;
      short8 bh = wgf[(ct*2 + 0)*64 + lane];
      short8 bl = wgf[(ct*2 + 1)*64 + lane];
      ag[0][c] = __builtin_amdgcn_mfma_f32_16x16x32_bf16(g0h, bh, ag[0][c], 0, 0, 0);
      ag[0][c] = __builtin_amdgcn_mfma_f32_16x16x32_bf16(g0h, bl, ag[0][c], 0, 0, 0);
      ag[0][c] = __builtin_amdgcn_mfma_f32_16x16x32_bf16(g0l, bh, ag[0][c], 0, 0, 0);
      ag[1][c] = __builtin_amdgcn_mfma_f32_16x16x32_bf16(g1h, bh, ag[1][c], 0, 0, 0);
      ag[1][c] = __builtin_amdgcn_mfma_f32_16x16x32_bf16(g1h, bl, ag[1][c], 0, 0, 0);
      ag[1][c] = __builtin_amdgcn_mfma_f32_16x16x32_bf16(g1l, bh, ag[1][c], 0, 0, 0);
    }
  }

  // --- epilogue: vp = ssp(am + bj) * ag; atomic scatter on idx_i ---
#pragma unroll
  for (int c = 0; c < 2; ++c){
    const int col = (w * 2 + c) * 16 + l15;
    const float bjv = bj[col];
#pragma unroll
    for (int rt = 0; rt < 2; ++rt){
#pragma unroll
      for (int r = 0; r < 4; ++r){
        const int row = rt * 16 + lq * 4 + r;
        const int ii  = ii_s[row];
        if (ii >= 0){
          float vp = ssp(am[rt][c][r] + bjv) * ag[rt][c][r];
          atomicAdd(&vacc[(size_t)ii * 128 + col], vp);
        }
      }
    }
  }
}

// ---------- fused atom-side chain (float32 output) ----------
// NOTE: vacc aliases out[0 : N*128] (the "o" half). Per block, vacc rows are fully
// consumed (layer 0) before any store to o (kernel end); tail-clamped reads are
// discarded. No __restrict__ on vacc/out because of the alias.
__global__ __launch_bounds__(128) void k_chain(
    const float* __restrict__ x, const float* vacc,
    const float* __restrict__ Wi, const float* __restrict__ bi,
    const float* __restrict__ Wf, const float* __restrict__ bf_,
    const float* __restrict__ u,
    const float* __restrict__ Wint, const float* __restrict__ bint,
    const float* __restrict__ Watm, const float* __restrict__ batm,
    const float* __restrict__ Wout, const float* __restrict__ bout,
    float* out, int N, int ni, int na, int no)
{
  __shared__ __align__(16) float arow[16][128];
  const int tid = threadIdx.x;
  const int r0 = blockIdx.x * 16;

  float xar[16], vreg[16], hreg[16], acc[16];

  for (int r = 0; r < 16; ++r){
    int row = r0 + r; if (row >= N) row = N - 1;
    float xav = ssp(x[(size_t)row*128 + tid]);
    xar[r] = xav;
    arow[r][tid] = xav;
  }
  __syncthreads();

  auto gemm = [&](const float* __restrict__ W){
#pragma unroll
    for (int r = 0; r < 16; ++r) acc[r] = 0.f;
    for (int k4 = 0; k4 < 32; ++k4){
      float w0 = W[(k4*4 + 0)*128 + tid];
      float w1 = W[(k4*4 + 1)*128 + tid];
      float w2 = W[(k4*4 + 2)*128 + tid];
      float w3 = W[(k4*4 + 3)*128 + tid];
#pragma unroll
      for (int r = 0; r < 16; ++r){
        float4 a = *(const float4*)&arow[r][k4*4];
        acc[r] += a.x*w0 + a.y*w1 + a.z*w2 + a.w*w3;
      }
    }
  };

  // layer 0: v = vacc + ssp(xa @ Wi + bi)
  gemm(Wi);
  {
    const float bv = bi[tid];
    for (int r = 0; r < 16; ++r){
      int row = r0 + r; if (row >= N) row = N - 1;
      vreg[r] = vacc[(size_t)row*128 + tid] + ssp(acc[r] + bv);
    }
  }
  __syncthreads();
  for (int r = 0; r < 16; ++r) arow[r][tid] = ssp(vreg[r]);
  __syncthreads();

  for (int kk = 0; kk < ni; ++kk){
    const float* W = Wint + (size_t)kk * 16384;
    const float bv = bint[kk*128 + tid];
    gemm(W);
    __syncthreads();
    for (int r = 0; r < 16; ++r) arow[r][tid] = ssp(acc[r] + bv);
    __syncthreads();
    gemm(W);
    for (int r = 0; r < 16; ++r) vreg[r] += acc[r] + bv;
    __syncthreads();
    for (int r = 0; r < 16; ++r) arow[r][tid] = ssp(vreg[r]);
    __syncthreads();
  }

  gemm(Wf);
  {
    const float bv = bf_[tid], uv = u[tid];
    for (int r = 0; r < 16; ++r) hreg[r] = acc[r] + bv + uv * xar[r];
  }
  __syncthreads();
  for (int r = 0; r < 16; ++r) arow[r][tid] = ssp(hreg[r]);
  __syncthreads();

  for (int kk = 0; kk < na; ++kk){
    const float* W = Watm + (size_t)kk * 16384;
    const float bv = batm[kk*128 + tid];
    gemm(W);
    __syncthreads();
    for (int r = 0; r < 16; ++r) arow[r][tid] = ssp(acc[r] + bv);
    __syncthreads();
    gemm(W);
    for (int r = 0; r < 16; ++r) hreg[r] += acc[r] + bv;
    __syncthreads();
    for (int r = 0; r < 16; ++r) arow[r][tid] = ssp(hreg[r]);
    __syncthreads();
  }

  for (int r = 0; r < 16; ++r){
    int row = r0 + r;
    if (row < N) out[(size_t)N*128 + (size_t)row*128 + tid] = hreg[r];
  }

  for (int kk = 0; kk < no; ++kk){
    const float* W = Wout + (size_t)kk * 16384;
    const float bv = bout[kk*128 + tid];
    gemm(W);
    __syncthreads();
    for (int r = 0; r < 16; ++r) arow[r][tid] = ssp(acc[r] + bv);
    __syncthreads();
    gemm(W);
    for (int r = 0; r < 16; ++r) hreg[r] += acc[r] + bv;
    if (kk + 1 < no){
      __syncthreads();
      for (int r = 0; r < 16; ++r) arow[r][tid] = ssp(hreg[r]);
      __syncthreads();
    }
  }

  for (int r = 0; r < 16; ++r){
    int row = r0 + r;
    if (row < N) out[(size_t)row*128 + tid] = ssp(hreg[r]);
  }
}

// ---------- launch ----------
extern "C" void kernel_launch(void* const* d_in, const int* in_sizes, int n_in,
                              void* d_out, int out_size, void* d_ws, size_t ws_size,
                              hipStream_t stream)
{
  const float* x    = (const float*)d_in[0];
  const float* g    = (const float*)d_in[1];
  const float* Wf   = (const float*)d_in[2];
  const float* bf_  = (const float*)d_in[3];
  const float* Wg   = (const float*)d_in[4];
  const float* Wj   = (const float*)d_in[5];
  const float* bj   = (const float*)d_in[6];
  const float* Wi   = (const float*)d_in[7];
  const float* bi   = (const float*)d_in[8];
  const float* u    = (const float*)d_in[9];
  const float* Wint = (const float*)d_in[10];
  const float* bint = (const float*)d_in[11];
  const float* Watm = (const float*)d_in[12];
  const float* batm = (const float*)d_in[13];
  const float* Wout = (const float*)d_in[14];
  const float* bout = (const float*)d_in[15];
  const int* idx_i  = (const int*)d_in[16];
  const int* idx_j  = (const int*)d_in[17];

  const int N  = in_sizes[0] / 128;
  const int E  = in_sizes[16];
  const int ni = in_sizes[10] / 16384;
  const int na = in_sizes[12] / 16384;
  const int no = in_sizes[14] / 16384;

  // vacc aliases the o-half of d_out (safe: consumed before o is written).
  // d_ws holds only the split-bf16 W fragments: Wj 64 KB + Wg 16 KB.
  float* vacc = (float*)d_out;
  unsigned short* wjf = (unsigned short*)d_ws;
  unsigned short* wgf = wjf + 4096 * 8;   // after 64 KB of Wj frags

  hipMemsetAsync(vacc, 0, (size_t)N * 128 * sizeof(float), stream);
  k_wconv<<<dim3(10), dim3(256), 0, stream>>>(Wj, Wg, wjf, wgf);
  k_edge <<<dim3((E + 31)/32), dim3(256), 0, stream>>>(x, g, idx_i, idx_j,
                                                       (const short8*)wjf, (const short8*)wgf,
                                                       bj, vacc, E);
  k_chain<<<dim3((N + 15)/16), dim3(128), 0, stream>>>(x, vacc,
                                                       Wi, bi, Wf, bf_, u,
                                                       Wint, bint, Watm, batm, Wout, bout,
                                                       (float*)d_out, N, ni, na, no);
}

// Round 3
// 581.266 us; speedup vs baseline: 3.7608x; 1.8814x over previous
//
#include <hip/hip_runtime.h>
#include <stdint.h>

#define LOG2F 0.693147180559945f

typedef __attribute__((ext_vector_type(8))) short short8;
typedef __attribute__((ext_vector_type(4))) float f32x4;

// shifted softplus: softplus(x) - log(2), stable form
__device__ __forceinline__ float ssp(float x){
  float t = __expf(-fabsf(x));
  return fmaxf(x, 0.0f) + __logf(1.0f + t) - LOG2F;
}

// fp32 -> bf16 round-to-nearest-even (16-bit pattern in low bits)
__device__ __forceinline__ uint32_t bf16rn(float x){
  uint32_t u = __float_as_uint(x);
  return (u + 0x7fffu + ((u >> 16) & 1u)) >> 16;
}
// split x ~= hi + lo (both bf16). hi RNE, lo = RNE(x - hi): ~16 mantissa bits kept.
__device__ __forceinline__ void split2(float x, unsigned short &h, unsigned short &l){
  uint32_t hb = bf16rn(x);
  h = (unsigned short)hb;
  float hf = __uint_as_float(hb << 16);
  l = (unsigned short)bf16rn(x - hf);
}

// ============================================================================
// MFMA fragment packing (mfma_f32_16x16x32_bf16) — HW-validated in round 2:
//   A-frag: lane l, elem i <- A[l&15][(l>>4)*8 + i]
//   B-frag: lane l, elem i <- B[(l>>4)*8 + i][l&15]
//   C/D   : lane l, reg  r -> C[(l>>4)*4 + r][l&15]
// Split-bf16 GEMM: D += Ah*Bh + Ah*Bl + Al*Bh  (3 MFMAs, fp32 accumulate)
// ============================================================================

// ---------- W pre-conversion into split-bf16 B-fragment layout ----------
// ws layout (uint4 = short8 granules of 16B):
//   slot m in [0, nmat): matrix frags, 4096 granules each (64 KB)
//     m=0: Wj | m=1: Wi | m=2..1+ni: Wint[k] | m=2+ni: Wf
//     m=3+ni..2+ni+na: Watm[k] | m=3+ni+na..: Wout[k]
//   slot nmat: Wg frags (1024 granules used)
__global__ __launch_bounds__(256) void k_wconv(
    const float* __restrict__ Wj, const float* __restrict__ Wg,
    const float* __restrict__ Wi, const float* __restrict__ Wf,
    const float* __restrict__ Wint, const float* __restrict__ Watm,
    const float* __restrict__ Wout,
    unsigned short* __restrict__ ws, int ni, int na, int no)
{
  const int nmat = 3 + ni + na + no;
  int t = blockIdx.x * 256 + threadIdx.x;
  int m = t >> 11, r = t & 2047;
  if (m < nmat){
    const float* src;
    if      (m == 0)           src = Wj;
    else if (m == 1)           src = Wi;
    else if (m <= 1 + ni)      src = Wint + (size_t)(m - 2) * 16384;
    else if (m == 2 + ni)      src = Wf;
    else if (m <= 2 + ni + na) src = Watm + (size_t)(m - 3 - ni) * 16384;
    else                       src = Wout + (size_t)(m - 3 - ni - na) * 16384;
    int lane = r & 63, s = (r >> 6) & 3, ct = r >> 8;
    int col = ct * 16 + (lane & 15);
    int k0  = s * 32 + (lane >> 4) * 8;
    union { unsigned short u[8]; uint4 v; } H, L;
#pragma unroll
    for (int i = 0; i < 8; ++i) split2(src[(size_t)(k0 + i) * 128 + col], H.u[i], L.u[i]);
    ((uint4*)ws)[(size_t)m * 4096 + ((ct * 4 + s) * 2 + 0) * 64 + lane] = H.v;
    ((uint4*)ws)[(size_t)m * 4096 + ((ct * 4 + s) * 2 + 1) * 64 + lane] = L.v;
  } else {
    int uu = t - nmat * 2048;
    if (uu < 512){
      int lane = uu & 63, ct = uu >> 6;
      int col = ct * 16 + (lane & 15);
      int k0  = (lane >> 4) * 8;
      union { unsigned short u8[8]; uint4 v; } H, L;
#pragma unroll
      for (int i = 0; i < 8; ++i) split2(Wg[(size_t)(k0 + i) * 128 + col], H.u8[i], L.u8[i]);
      ((uint4*)ws)[(size_t)nmat * 4096 + (ct * 2 + 0) * 64 + lane] = H.v;
      ((uint4*)ws)[(size_t)nmat * 4096 + (ct * 2 + 1) * 64 + lane] = L.v;
    }
  }
}

// ---------- edge kernel: vacc[idx_i] += ssp(ssp(x)[idx_j]@Wj + bj) * (g@Wg) ----------
__global__ __launch_bounds__(256) void k_edge(
    const float* __restrict__ x, const float* __restrict__ g,
    const int* __restrict__ idx_i, const int* __restrict__ idx_j,
    const short8* __restrict__ wjf, const short8* __restrict__ wgf,
    const float* __restrict__ bj, float* vacc, int E)
{
  __shared__ short8 ahl[1024];   // 16 KB: message A, 32 rows x 128 k, hi+lo
  __shared__ short8 ghl[256];    //  4 KB: gate A,    32 rows x  32 k, hi+lo
  __shared__ int    ii_s[32];

  const int t    = threadIdx.x;
  const int lane = t & 63;
  const int w    = t >> 6;
  const int l15  = lane & 15;
  const int lq   = lane >> 4;
  const int e0   = blockIdx.x * 32;

  {
    const int row = t >> 3, kseg = t & 7;
    int e = e0 + row; if (e >= E) e = E - 1;
    const int j = idx_j[e];
    const float4* xp = (const float4*)(x + (size_t)j * 128 + kseg * 16);
    short8 fh0, fh1, fl0, fl1;
#pragma unroll
    for (int q = 0; q < 4; ++q){
      float4 f4 = xp[q];
      float vv[4] = {f4.x, f4.y, f4.z, f4.w};
#pragma unroll
      for (int uu = 0; uu < 4; ++uu){
        unsigned short hh, ll;
        split2(ssp(vv[uu]), hh, ll);
        int i = q * 4 + uu;
        if (i < 8){ fh0[i]   = (short)hh; fl0[i]   = (short)ll; }
        else      { fh1[i-8] = (short)hh; fl1[i-8] = (short)ll; }
      }
    }
    const int q0 = kseg * 2;
    ahl[0*512 + (q0+0)*32 + (row ^ (q0+0))] = fh0;
    ahl[0*512 + (q0+1)*32 + (row ^ (q0+1))] = fh1;
    ahl[1*512 + (q0+0)*32 + (row ^ (q0+0))] = fl0;
    ahl[1*512 + (q0+1)*32 + (row ^ (q0+1))] = fl1;
  }
  if (t < 64){
    const int row = t >> 1, kseg = t & 1;
    int e = e0 + row; if (e >= E) e = E - 1;
    const float4* gp = (const float4*)(g + (size_t)e * 32 + kseg * 16);
    short8 fh0, fh1, fl0, fl1;
#pragma unroll
    for (int q = 0; q < 4; ++q){
      float4 f4 = gp[q];
      float vv[4] = {f4.x, f4.y, f4.z, f4.w};
#pragma unroll
      for (int uu = 0; uu < 4; ++uu){
        unsigned short hh, ll;
        split2(vv[uu], hh, ll);
        int i = q * 4 + uu;
        if (i < 8){ fh0[i]   = (short)hh; fl0[i]   = (short)ll; }
        else      { fh1[i-8] = (short)hh; fl1[i-8] = (short)ll; }
      }
    }
    const int q0 = kseg * 2;
    ghl[0*128 + (q0+0)*32 + (row ^ (q0+0))] = fh0;
    ghl[0*128 + (q0+1)*32 + (row ^ (q0+1))] = fh1;
    ghl[1*128 + (q0+0)*32 + (row ^ (q0+0))] = fl0;
    ghl[1*128 + (q0+1)*32 + (row ^ (q0+1))] = fl1;
  }
  if (t >= 64 && t < 96){
    int rr = t - 64; int e = e0 + rr;
    ii_s[rr] = (e < E) ? idx_i[e] : -1;
  }
  __syncthreads();

  f32x4 am[2][2], ag[2][2];
#pragma unroll
  for (int a = 0; a < 2; ++a)
#pragma unroll
    for (int b = 0; b < 2; ++b){
      am[a][b] = (f32x4){0.f, 0.f, 0.f, 0.f};
      ag[a][b] = (f32x4){0.f, 0.f, 0.f, 0.f};
    }

#pragma unroll
  for (int s = 0; s < 4; ++s){
    const int q = s * 4 + lq;
    short8 a0h = ahl[0*512 + q*32 + ((l15     ) ^ q)];
    short8 a0l = ahl[1*512 + q*32 + ((l15     ) ^ q)];
    short8 a1h = ahl[0*512 + q*32 + ((16 + l15) ^ q)];
    short8 a1l = ahl[1*512 + q*32 + ((16 + l15) ^ q)];
#pragma unroll
    for (int c = 0; c < 2; ++c){
      const int ct = w * 2 + c;
      short8 bh = wjf[((ct*4 + s)*2 + 0)*64 + lane];
      short8 bl = wjf[((ct*4 + s)*2 + 1)*64 + lane];
      am[0][c] = __builtin_amdgcn_mfma_f32_16x16x32_bf16(a0h, bh, am[0][c], 0, 0, 0);
      am[0][c] = __builtin_amdgcn_mfma_f32_16x16x32_bf16(a0h, bl, am[0][c], 0, 0, 0);
      am[0][c] = __builtin_amdgcn_mfma_f32_16x16x32_bf16(a0l, bh, am[0][c], 0, 0, 0);
      am[1][c] = __builtin_amdgcn_mfma_f32_16x16x32_bf16(a1h, bh, am[1][c], 0, 0, 0);
      am[1][c] = __builtin_amdgcn_mfma_f32_16x16x32_bf16(a1h, bl, am[1][c], 0, 0, 0);
      am[1][c] = __builtin_amdgcn_mfma_f32_16x16x32_bf16(a1l, bh, am[1][c], 0, 0, 0);
    }
  }
  {
    const int q = lq;
    short8 g0h = ghl[0*128 + q*32 + ((l15     ) ^ q)];
    short8 g0l = ghl[1*128 + q*32 + ((l15     ) ^ q)];
    short8 g1h = ghl[0*128 + q*32 + ((16 + l15) ^ q)];
    short8 g1l = ghl[1*128 + q*32 + ((16 + l15) ^ q)];
#pragma unroll
    for (int c = 0; c < 2; ++c){
      const int ct = w * 2 + c;
      short8 bh = wgf[(ct*2 + 0)*64 + lane];
      short8 bl = wgf[(ct*2 + 1)*64 + lane];
      ag[0][c] = __builtin_amdgcn_mfma_f32_16x16x32_bf16(g0h, bh, ag[0][c], 0, 0, 0);
      ag[0][c] = __builtin_amdgcn_mfma_f32_16x16x32_bf16(g0h, bl, ag[0][c], 0, 0, 0);
      ag[0][c] = __builtin_amdgcn_mfma_f32_16x16x32_bf16(g0l, bh, ag[0][c], 0, 0, 0);
      ag[1][c] = __builtin_amdgcn_mfma_f32_16x16x32_bf16(g1h, bh, ag[1][c], 0, 0, 0);
      ag[1][c] = __builtin_amdgcn_mfma_f32_16x16x32_bf16(g1h, bl, ag[1][c], 0, 0, 0);
      ag[1][c] = __builtin_amdgcn_mfma_f32_16x16x32_bf16(g1l, bh, ag[1][c], 0, 0, 0);
    }
  }

#pragma unroll
  for (int c = 0; c < 2; ++c){
    const int col = (w * 2 + c) * 16 + l15;
    const float bjv = bj[col];
#pragma unroll
    for (int rt = 0; rt < 2; ++rt){
#pragma unroll
      for (int r = 0; r < 4; ++r){
        const int row = rt * 16 + lq * 4 + r;
        const int ii  = ii_s[row];
        if (ii >= 0){
          float vp = ssp(am[rt][c][r] + bjv) * ag[rt][c][r];
          atomicAdd(&vacc[(size_t)ii * 128 + col], vp);
        }
      }
    }
  }
}

// ---------- fused atom-side chain, MFMA version ----------
// 32 rows/block, 256 threads = 4 waves; wave w owns cols [32w, 32w+32).
// State (v,h,xa) lives in C-fragment-layout registers (16 f32/lane each).
// Per GEMM: state -> ssp -> f32 LDS (stride 132) -> split-bf16 A-frags -> MFMA.
// NOTE: vacc aliases out[0 : N*128]; each block reads only its own vacc rows
// (layer 0) and writes o to those rows only at kernel end. Tail clamps read
// row N-1, which belongs to the same (last) block. No cross-block hazard.
__global__ __launch_bounds__(256) void k_chain(
    const float* __restrict__ x, const float* vacc,
    const short8* __restrict__ wcf,   // chain weight frags: slot*4096 granules
    const float* __restrict__ bi, const float* __restrict__ bf_,
    const float* __restrict__ u,
    const float* __restrict__ bint, const float* __restrict__ batm,
    const float* __restrict__ bout,
    float* out, int N, int ni, int na, int no)
{
  __shared__ __align__(16) float arow[32][132];  // padded: +4 breaks bank collisions
  __shared__ short8 ahl[1024];

  const int t    = threadIdx.x;
  const int lane = t & 63;
  const int w    = t >> 6;
  const int l15  = lane & 15;
  const int lq   = lane >> 4;
  const int r0   = blockIdx.x * 32;
  const int srow = t >> 3, skseg = t & 7;   // staging coords: row, 16-elem k-seg

  const int col0 = (w*2 + 0)*16 + l15;
  const int col1 = (w*2 + 1)*16 + l15;

  f32x4 am[2][2];

  // split own 16-f32 slice of arow into 4 frag granules
  auto stage = [&](){
    const float* p = &arow[srow][skseg*16];
    short8 fh0, fh1, fl0, fl1;
#pragma unroll
    for (int i = 0; i < 8; ++i){
      unsigned short hh, ll;
      split2(p[i], hh, ll);
      fh0[i] = (short)hh; fl0[i] = (short)ll;
    }
#pragma unroll
    for (int i = 0; i < 8; ++i){
      unsigned short hh, ll;
      split2(p[8+i], hh, ll);
      fh1[i] = (short)hh; fl1[i] = (short)ll;
    }
    const int q0 = skseg * 2;
    ahl[0*512 + (q0+0)*32 + (srow ^ (q0+0))] = fh0;
    ahl[0*512 + (q0+1)*32 + (srow ^ (q0+1))] = fh1;
    ahl[1*512 + (q0+0)*32 + (srow ^ (q0+0))] = fl0;
    ahl[1*512 + (q0+1)*32 + (srow ^ (q0+1))] = fl1;
  };

  auto gemm = [&](const short8* __restrict__ wf){
#pragma unroll
    for (int a = 0; a < 2; ++a)
#pragma unroll
      for (int b = 0; b < 2; ++b) am[a][b] = (f32x4){0.f, 0.f, 0.f, 0.f};
#pragma unroll
    for (int s = 0; s < 4; ++s){
      const int q = s * 4 + lq;
      short8 a0h = ahl[0*512 + q*32 + ((l15     ) ^ q)];
      short8 a0l = ahl[1*512 + q*32 + ((l15     ) ^ q)];
      short8 a1h = ahl[0*512 + q*32 + ((16 + l15) ^ q)];
      short8 a1l = ahl[1*512 + q*32 + ((16 + l15) ^ q)];
#pragma unroll
      for (int c = 0; c < 2; ++c){
        const int ct = w * 2 + c;
        short8 bh = wf[((ct*4 + s)*2 + 0)*64 + lane];
        short8 bl = wf[((ct*4 + s)*2 + 1)*64 + lane];
        am[0][c] = __builtin_amdgcn_mfma_f32_16x16x32_bf16(a0h, bh, am[0][c], 0, 0, 0);
        am[0][c] = __builtin_amdgcn_mfma_f32_16x16x32_bf16(a0h, bl, am[0][c], 0, 0, 0);
        am[0][c] = __builtin_amdgcn_mfma_f32_16x16x32_bf16(a0l, bh, am[0][c], 0, 0, 0);
        am[1][c] = __builtin_amdgcn_mfma_f32_16x16x32_bf16(a1h, bh, am[1][c], 0, 0, 0);
        am[1][c] = __builtin_amdgcn_mfma_f32_16x16x32_bf16(a1h, bl, am[1][c], 0, 0, 0);
        am[1][c] = __builtin_amdgcn_mfma_f32_16x16x32_bf16(a1l, bh, am[1][c], 0, 0, 0);
      }
    }
  };

  // write ssp(state) into arow at this lane's C-layout positions
  auto put_ssp = [&](float (&st)[2][2][4]){
#pragma unroll
    for (int rt = 0; rt < 2; ++rt)
#pragma unroll
      for (int r = 0; r < 4; ++r){
        const int row = rt*16 + lq*4 + r;
        arow[row][col0] = ssp(st[rt][0][r]);
        arow[row][col1] = ssp(st[rt][1][r]);
      }
  };

  // full PhysNet residual on state st with weight frags wf and bias bvec
  auto residual = [&](float (&st)[2][2][4], const short8* wf, const float* bvec){
    const float b0 = bvec[col0], b1 = bvec[col1];
    put_ssp(st);                            // A = ssp(st)
    __syncthreads();
    stage();
    __syncthreads();
    gemm(wf);                               // am = ssp(st) @ W
#pragma unroll
    for (int rt = 0; rt < 2; ++rt)
#pragma unroll
      for (int r = 0; r < 4; ++r){          // A = ssp(am + b)
        const int row = rt*16 + lq*4 + r;
        arow[row][col0] = ssp(am[rt][0][r] + b0);
        arow[row][col1] = ssp(am[rt][1][r] + b1);
      }
    __syncthreads();
    stage();
    __syncthreads();
    gemm(wf);                               // am = ssp(h1) @ W
#pragma unroll
    for (int rt = 0; rt < 2; ++rt)
#pragma unroll
      for (int r = 0; r < 4; ++r){
        st[rt][0][r] += am[rt][0][r] + b0;
        st[rt][1][r] += am[rt][1][r] + b1;
      }
  };

  // ---- init: xa = ssp(x rows); write arow + frags (own slices only) ----
  {
    int row = r0 + srow; if (row >= N) row = N - 1;
    const float4* xp = (const float4*)(x + (size_t)row*128 + skseg*16);
    float* p = &arow[srow][skseg*16];
#pragma unroll
    for (int qq = 0; qq < 4; ++qq){
      float4 f4 = xp[qq];
      p[qq*4+0] = ssp(f4.x); p[qq*4+1] = ssp(f4.y);
      p[qq*4+2] = ssp(f4.z); p[qq*4+3] = ssp(f4.w);
    }
    stage();
  }
  __syncthreads();

  float xar[2][2][4];
#pragma unroll
  for (int rt = 0; rt < 2; ++rt)
#pragma unroll
    for (int r = 0; r < 4; ++r){
      const int row = rt*16 + lq*4 + r;
      xar[rt][0][r] = arow[row][col0];
      xar[rt][1][r] = arow[row][col1];
    }

  // layer 0: v = vacc + ssp(xa @ Wi + bi)
  gemm(wcf + 0);
  float vst[2][2][4];
  {
    const float b0 = bi[col0], b1 = bi[col1];
#pragma unroll
    for (int rt = 0; rt < 2; ++rt)
#pragma unroll
      for (int r = 0; r < 4; ++r){
        int row = r0 + rt*16 + lq*4 + r; if (row >= N) row = N - 1;
        vst[rt][0][r] = vacc[(size_t)row*128 + col0] + ssp(am[rt][0][r] + b0);
        vst[rt][1][r] = vacc[(size_t)row*128 + col1] + ssp(am[rt][1][r] + b1);
      }
  }

  // interaction residuals
  for (int kk = 0; kk < ni; ++kk)
    residual(vst, wcf + (size_t)(1 + kk) * 4096, bint + kk*128);

  // h = u*xa + ssp(v) @ Wf + bf
  put_ssp(vst);
  __syncthreads();
  stage();
  __syncthreads();
  gemm(wcf + (size_t)(1 + ni) * 4096);
  float hst[2][2][4];
  {
    const float b0 = bf_[col0], b1 = bf_[col1];
    const float u0 = u[col0],   u1 = u[col1];
#pragma unroll
    for (int rt = 0; rt < 2; ++rt)
#pragma unroll
      for (int r = 0; r < 4; ++r){
        hst[rt][0][r] = u0 * xar[rt][0][r] + am[rt][0][r] + b0;
        hst[rt][1][r] = u1 * xar[rt][1][r] + am[rt][1][r] + b1;
      }
  }

  // atom residuals
  for (int kk = 0; kk < na; ++kk)
    residual(hst, wcf + (size_t)(2 + ni + kk) * 4096, batm + kk*128);

  // store h (second tuple element)
#pragma unroll
  for (int rt = 0; rt < 2; ++rt)
#pragma unroll
    for (int r = 0; r < 4; ++r){
      const int row = r0 + rt*16 + lq*4 + r;
      if (row < N){
        out[(size_t)N*128 + (size_t)row*128 + col0] = hst[rt][0][r];
        out[(size_t)N*128 + (size_t)row*128 + col1] = hst[rt][1][r];
      }
    }

  // output residuals (o evolves in hst)
  for (int kk = 0; kk < no; ++kk)
    residual(hst, wcf + (size_t)(2 + ni + na + kk) * 4096, bout + kk*128);

  // o = ssp(o): store first tuple element
#pragma unroll
  for (int rt = 0; rt < 2; ++rt)
#pragma unroll
    for (int r = 0; r < 4; ++r){
      const int row = r0 + rt*16 + lq*4 + r;
      if (row < N){
        out[(size_t)row*128 + col0] = ssp(hst[rt][0][r]);
        out[(size_t)row*128 + col1] = ssp(hst[rt][1][r]);
      }
    }
}

// ---------- launch ----------
extern "C" void kernel_launch(void* const* d_in, const int* in_sizes, int n_in,
                              void* d_out, int out_size, void* d_ws, size_t ws_size,
                              hipStream_t stream)
{
  const float* x    = (const float*)d_in[0];
  const float* g    = (const float*)d_in[1];
  const float* Wf   = (const float*)d_in[2];
  const float* bf_  = (const float*)d_in[3];
  const float* Wg   = (const float*)d_in[4];
  const float* Wj   = (const float*)d_in[5];
  const float* bj   = (const float*)d_in[6];
  const float* Wi   = (const float*)d_in[7];
  const float* bi   = (const float*)d_in[8];
  const float* u    = (const float*)d_in[9];
  const float* Wint = (const float*)d_in[10];
  const float* bint = (const float*)d_in[11];
  const float* Watm = (const float*)d_in[12];
  const float* batm = (const float*)d_in[13];
  const float* Wout = (const float*)d_in[14];
  const float* bout = (const float*)d_in[15];
  const int* idx_i  = (const int*)d_in[16];
  const int* idx_j  = (const int*)d_in[17];

  const int N  = in_sizes[0] / 128;
  const int E  = in_sizes[16];
  const int ni = in_sizes[10] / 16384;
  const int na = in_sizes[12] / 16384;
  const int no = in_sizes[14] / 16384;

  const int nmat = 3 + ni + na + no;   // Wj, Wi, Wint[ni], Wf, Watm[na], Wout[no]

  // vacc aliases the o-half of d_out (consumed before o is written).
  // d_ws: (nmat+1) x 64 KB of split-bf16 weight fragments.
  float* vacc = (float*)d_out;
  short8* wsf = (short8*)d_ws;
  const short8* wjf = wsf;                               // slot 0
  const short8* wcf = wsf + (size_t)1 * 4096;            // slots 1..nmat-1 (chain)
  const short8* wgf = wsf + (size_t)nmat * 4096;         // slot nmat (Wg)

  hipMemsetAsync(vacc, 0, (size_t)N * 128 * sizeof(float), stream);
  k_wconv<<<dim3((nmat + 1) * 8), dim3(256), 0, stream>>>(Wj, Wg, Wi, Wf, Wint, Watm, Wout,
                                                          (unsigned short*)d_ws, ni, na, no);
  k_edge <<<dim3((E + 31)/32), dim3(256), 0, stream>>>(x, g, idx_i, idx_j,
                                                       wjf, wgf, bj, vacc, E);
  k_chain<<<dim3((N + 31)/32), dim3(256), 0, stream>>>(x, vacc, wcf,
                                                       bi, bf_, u, bint, batm, bout,
                                                       (float*)d_out, N, ni, na, no);
}